// Round 1
// baseline (444.041 us; speedup 1.0000x reference)
//
#include <hip/hip_runtime.h>
#include <hip/hip_bf16.h>
#include <math.h>

#define T_NCE 0.07f
#define EPSF 1e-7f

// ---------------- workspace layout (float units) ----------------
// [0]        : dtype flag (int; 1 = bf16 inputs, 0 = f32 inputs)
// [8]        : acc loss_cls
// [9]        : acc loss_rel
// [10]       : acc loss_act
// [32 ..)    : means  4 * 64 * 2048   (HAm, EAm, HBm, EBm)
// then       : dots   2 * 64 * 150    (which0: qA.EBrow, which1: qB.EArow)
// then       : nsq    2 * 64 * 150    (||EBrow||^2 / ||EArow||^2)
// then       : qk     6 * 64          (nqa, nka, nqb, nkb, dot(qa,ka), dot(qb,kb))
#define WS_MEANS 32
#define WS_DOTS  (WS_MEANS + 4 * 64 * 2048)
#define WS_NSQ   (WS_DOTS + 2 * 64 * 150)
#define WS_QK    (WS_NSQ + 2 * 64 * 150)

__device__ __forceinline__ float bf2f(unsigned short h) {
    unsigned int u = ((unsigned int)h) << 16;
    float f;
    __builtin_memcpy(&f, &u, 4);
    return f;
}

__device__ __forceinline__ float ldf(const void* p, int i, int bf) {
    if (bf) return bf2f(((const unsigned short*)p)[i]);
    return ((const float*)p)[i];
}

struct F8 { float v[8]; };

// load 8 consecutive elements starting at element i (i % 8 == 0)
__device__ __forceinline__ F8 ld8(const void* p, int i, int bf) {
    F8 r;
    if (bf) {
        uint4 u = *((const uint4*)((const unsigned short*)p + i));
        const unsigned short* hs = (const unsigned short*)&u;
#pragma unroll
        for (int k = 0; k < 8; k++) r.v[k] = bf2f(hs[k]);
    } else {
        const float4* q = (const float4*)((const float*)p + i);
        float4 a = q[0], b = q[1];
        r.v[0] = a.x; r.v[1] = a.y; r.v[2] = a.z; r.v[3] = a.w;
        r.v[4] = b.x; r.v[5] = b.y; r.v[6] = b.z; r.v[7] = b.w;
    }
    return r;
}

__device__ __forceinline__ float block_reduce256(float v, float* sbuf) {
    int t = threadIdx.x;
    sbuf[t] = v;
    __syncthreads();
    for (int s = 128; s > 0; s >>= 1) {
        if (t < s) sbuf[t] += sbuf[t + s];
        __syncthreads();
    }
    float r = sbuf[0];
    __syncthreads();
    return r;
}

// ---------------- kernel 0: dtype probe + accumulator init ----------------
__global__ void k_init(const void* video_scores, float* ws) {
    if (threadIdx.x == 0) {
        const unsigned short* u = (const unsigned short*)video_scores;
        int cnt = 0;
        // even bf16-slots: real values if buffer is bf16; random mantissa bits if f32
        for (int i = 0; i < 64; i++) {
            unsigned short h = u[2 * i];
            int e = (h >> 7) & 0xFF;
            int sgn = (h >> 15) & 1;
            if (!sgn && e >= 90 && e <= 126) cnt++;
        }
        ((int*)ws)[0] = (cnt >= 56) ? 1 : 0;
        ws[8] = 0.f; ws[9] = 0.f; ws[10] = 0.f;
    }
}

// ---------------- kernel 1: per-batch means of HA/EA/HB/EB ----------------
// grid 256 = arr(4) * b(64); block 256, each thread 8 consecutive channels
__global__ void k_means(const void* HA, const void* EA, const void* HB, const void* EB,
                        float* ws) {
    int bf = ((const int*)ws)[0];
    int arr = blockIdx.x >> 6;
    int b = blockIdx.x & 63;
    const void* src = (arr == 0) ? HA : (arr == 1) ? EA : (arr == 2) ? HB : EB;
    int c0 = threadIdx.x * 8;
    float acc[8];
#pragma unroll
    for (int k = 0; k < 8; k++) acc[k] = 0.f;
    for (int j = 0; j < 150; j++) {
        F8 v = ld8(src, (b * 150 + j) * 2048 + c0, bf);
#pragma unroll
        for (int k = 0; k < 8; k++) acc[k] += v.v[k];
    }
    float* dst = ws + WS_MEANS + (arr * 64 + b) * 2048 + c0;
#pragma unroll
    for (int k = 0; k < 8; k++) dst[k] = acc[k] * (1.f / 150.f);
}

// ---------------- kernel 2: raw dots q.neg_row + row sumsq ----------------
// grid 640 = which(2) * b(64) * jchunk(5); block 256 = 4 waves, wave per j
__global__ void k_dots(const void* EA, const void* EB, float* ws) {
    int bf = ((const int*)ws)[0];
    __shared__ float qs[2048];
    int bi = blockIdx.x;
    int which = bi / 320;
    int rem = bi % 320;
    int b = rem / 5;
    int chunk = rem % 5;
    const float* q = ws + WS_MEANS + ((which == 0 ? 0 : 2) * 64 + b) * 2048;
    for (int i = threadIdx.x; i < 2048; i += 256) qs[i] = q[i];
    __syncthreads();
    const void* neg = (which == 0) ? EB : EA;
    int lane = threadIdx.x & 63;
    int wid = threadIdx.x >> 6;
    for (int j = chunk * 30 + wid; j < chunk * 30 + 30; j += 4) {
        int base = (b * 150 + j) * 2048;
        float dot = 0.f, nsq = 0.f;
#pragma unroll
        for (int it = 0; it < 4; it++) {
            int off = it * 512 + lane * 8;
            F8 v = ld8(neg, base + off, bf);
#pragma unroll
            for (int k = 0; k < 8; k++) {
                float x = v.v[k];
                dot += x * qs[off + k];
                nsq += x * x;
            }
        }
        for (int s = 32; s > 0; s >>= 1) {
            dot += __shfl_down(dot, s);
            nsq += __shfl_down(nsq, s);
        }
        if (lane == 0) {
            ws[WS_DOTS + (which * 64 + b) * 150 + j] = dot;
            ws[WS_NSQ + (which * 64 + b) * 150 + j] = nsq;
        }
    }
}

// ---------------- kernel 3: per-batch q/k norms and q.k dots ----------------
// grid 64 (one per batch), block 256
__global__ void k_qk(float* ws) {
    __shared__ float sbuf[256];
    int b = blockIdx.x, t = threadIdx.x;
    const float* m = ws + WS_MEANS;
    float p0 = 0, p1 = 0, p2 = 0, p3 = 0, p4 = 0, p5 = 0;
    for (int c = t; c < 2048; c += 256) {
        float qa = m[(0 * 64 + b) * 2048 + c];
        float ka = m[(1 * 64 + b) * 2048 + c];
        float qb = m[(2 * 64 + b) * 2048 + c];
        float kb = m[(3 * 64 + b) * 2048 + c];
        p0 += qa * qa; p1 += ka * ka; p2 += qb * qb;
        p3 += kb * kb; p4 += qa * ka; p5 += qb * kb;
    }
    float r;
    r = block_reduce256(p0, sbuf); if (t == 0) ws[WS_QK + 0 * 64 + b] = r;
    r = block_reduce256(p1, sbuf); if (t == 0) ws[WS_QK + 1 * 64 + b] = r;
    r = block_reduce256(p2, sbuf); if (t == 0) ws[WS_QK + 2 * 64 + b] = r;
    r = block_reduce256(p3, sbuf); if (t == 0) ws[WS_QK + 3 * 64 + b] = r;
    r = block_reduce256(p4, sbuf); if (t == 0) ws[WS_QK + 4 * 64 + b] = r;
    r = block_reduce256(p5, sbuf); if (t == 0) ws[WS_QK + 5 * 64 + b] = r;
}

// ---------------- kernel 4: loss_cls ----------------
__global__ void k_cls(const void* vs, const void* label, float* ws) {
    int bf = ((const int*)ws)[0];
    __shared__ float rowsum[64];
    __shared__ float sbuf[256];
    int t = threadIdx.x;
    if (t < 64) {
        float s = 0.f;
        for (int c = 0; c < 20; c++) s += ldf(label, t * 20 + c, bf);
        rowsum[t] = s;
    }
    __syncthreads();
    float local = 0.f;
    for (int i = t; i < 1280; i += 256) {
        int b = i / 20;
        float lab = ldf(label, i, bf) / rowsum[b];
        float v = ldf(vs, i, bf);
        v = fminf(fmaxf(v, EPSF), 1.f - EPSF);
        local += lab * logf(v) + (1.f - lab) * log1pf(-v);
    }
    float s = block_reduce256(local, sbuf);
    if (t == 0) ws[8] = -s / 1280.f;
}

// ---------------- kernel 5: loss_rel ----------------
__global__ void k_rel(const void* res, const void* red, float* ws) {
    int bf = ((const int*)ws)[0];
    __shared__ float sbuf[256];
    int stride = gridDim.x * 256;
    float local = 0.f;
    for (int i = blockIdx.x * 256 + threadIdx.x; i < 96000; i += stride) {
        float sv = ldf(res, i, bf);
        float dv = ldf(red, i, bf);
        local += (1.f - sv) * (1.f - sv) + dv * dv;
    }
    float s = block_reduce256(local, sbuf);
    if (threadIdx.x == 0) atomicAdd(&ws[9], s * (1.f / 96000.f));
}

// ---------------- kernel 6: loss_act ----------------
// part1: one thread per (t,d) of 750x11 windows; part2: grid-stride (a0-a2)^2
__global__ void k_act(const void* a0, const void* a2, float* ws) {
    int bf = ((const int*)ws)[0];
    __shared__ float sbuf[256];
    int id = blockIdx.x * 256 + threadIdx.x;
    float val = 0.f;
    if (id < 8250) {
        int tt = id / 11;
        int d = id % 11;
        int c = min(max(tt + d - 6, 0), 749);
        float wsum = 0.f, asum = 0.f;
        for (int b = 0; b < 64; b++) {
            float x = ldf(a0, b * 750 + tt, bf);
            float y = ldf(a0, b * 750 + c, bf);
            wsum += (x - y) * (x - y);
            float p = ldf(a2, b * 750 + tt, bf);
            float q = ldf(a2, b * 750 + c, bf);
            asum += fabsf(p - q);
        }
        val = __expf(-0.5f * wsum) * (asum * (1.f / 64.f));
    }
    float s1 = block_reduce256(val, sbuf);
    int stride = gridDim.x * 256;
    float local = 0.f;
    for (int i = id; i < 48000; i += stride) {
        float x = ldf(a0, i, bf) - ldf(a2, i, bf);
        local += x * x;
    }
    float s2 = block_reduce256(local, sbuf);
    if (threadIdx.x == 0) atomicAdd(&ws[10], s1 + s2 * (0.1f / 64.f));
}

// ---------------- kernel 7: NCE logsumexp + final combine ----------------
__global__ void k_final(const void* att, float* ws, void* out) {
    int bf = ((const int*)ws)[0];
    __shared__ float sbuf[256];
    int t = threadIdx.x;
    float loss_b = 0.f;
    if (t < 128) {
        int w = t >> 6;
        int b = t & 63;
        float nq = ws[WS_QK + (w == 0 ? 0 : 2) * 64 + b];
        float nk = ws[WS_QK + (w == 0 ? 1 : 3) * 64 + b];
        float dd = ws[WS_QK + (4 + w) * 64 + b];
        float invq = rsqrtf(nq);
        float lpos = dd * invq * rsqrtf(nk) * (1.f / T_NCE);
        float m = lpos, s = 1.f;
        for (int j = 0; j < 150; j++) {
            float raw = ws[WS_DOTS + (w * 64 + b) * 150 + j];
            float nn = ws[WS_NSQ + (w * 64 + b) * 150 + j];
            float a = ldf(att, b * 300 + w * 150 + j, bf);
            float lg = a * raw * invq * rsqrtf(nn) * (1.f / T_NCE);
            if (lg <= m) {
                s += expf(lg - m);
            } else {
                s = s * expf(m - lg) + 1.f;
                m = lg;
            }
        }
        loss_b = (m + logf(s)) - lpos;  // -log_softmax[0]
    }
    float snico_sum = block_reduce256(loss_b, sbuf);
    if (t == 0) {
        float snico = snico_sum * (1.f / 64.f);
        float cls = ws[8];
        float rel = ws[9];
        float act = ws[10];
        float total = cls + 0.01f * snico + act + 0.1f * rel;
        if (bf) {
            __hip_bfloat16* o = (__hip_bfloat16*)out;
            o[0] = __float2bfloat16(total);
            o[1] = __float2bfloat16(cls);
            o[2] = __float2bfloat16(snico);
            o[3] = __float2bfloat16(act);
            o[4] = __float2bfloat16(rel);
        } else {
            float* o = (float*)out;
            o[0] = total; o[1] = cls; o[2] = snico; o[3] = act; o[4] = rel;
        }
    }
}

extern "C" void kernel_launch(void* const* d_in, const int* in_sizes, int n_in,
                              void* d_out, int out_size, void* d_ws, size_t ws_size,
                              hipStream_t stream) {
    const void* video_scores = d_in[0];
    const void* label = d_in[1];
    const void* HA = d_in[2];
    const void* EA = d_in[3];
    const void* HB = d_in[4];
    const void* EB = d_in[5];
    const void* re_s = d_in[6];
    const void* re_d = d_in[7];
    const void* actioness = d_in[8];
    const void* actioness_2 = d_in[9];
    const void* att = d_in[10];
    float* ws = (float*)d_ws;

    k_init<<<1, 64, 0, stream>>>(video_scores, ws);
    k_means<<<256, 256, 0, stream>>>(HA, EA, HB, EB, ws);
    k_dots<<<640, 256, 0, stream>>>(EA, EB, ws);
    k_qk<<<64, 256, 0, stream>>>(ws);
    k_cls<<<1, 256, 0, stream>>>(video_scores, label, ws);
    k_rel<<<128, 256, 0, stream>>>(re_s, re_d, ws);
    k_act<<<33, 256, 0, stream>>>(actioness, actioness_2, ws);
    k_final<<<1, 256, 0, stream>>>(att, ws, d_out);
}

// Round 2
// 375.628 us; speedup vs baseline: 1.1821x; 1.1821x over previous
//
#include <hip/hip_runtime.h>
#include <hip/hip_bf16.h>
#include <math.h>

#define T_NCE 0.07f
#define EPSF 1e-7f

// ---------------- workspace layout (float units) ----------------
// [0]  : dtype flag (int; 1 = bf16 inputs, 0 = f32 inputs)
// [8]  : acc loss_cls   [9] : acc loss_rel
// [10] : acc loss_act   [11]: acc snico sum
// WS_MEANS : 4*64*2048 per-batch channel SUMS (not means; scale cancels in NCE)
// WS_DOTS  : 2*64*150 raw dots   WS_NSQ : 2*64*150 row sumsq
#define WS_MEANS 32
#define MEANS_N (4 * 64 * 2048)
#define WS_DOTS (WS_MEANS + MEANS_N)
#define WS_NSQ  (WS_DOTS + 2 * 64 * 150)

__device__ __forceinline__ float bf2f(unsigned short h) {
    unsigned int u = ((unsigned int)h) << 16;
    float f;
    __builtin_memcpy(&f, &u, 4);
    return f;
}

__device__ __forceinline__ float ldf(const void* p, int i, int bf) {
    if (bf) return bf2f(((const unsigned short*)p)[i]);
    return ((const float*)p)[i];
}

struct F8 { float v[8]; };

__device__ __forceinline__ F8 ld8(const void* p, int i, int bf) {
    F8 r;
    if (bf) {
        uint4 u = *((const uint4*)((const unsigned short*)p + i));
        const unsigned short* hs = (const unsigned short*)&u;
#pragma unroll
        for (int k = 0; k < 8; k++) r.v[k] = bf2f(hs[k]);
    } else {
        const float4* q = (const float4*)((const float*)p + i);
        float4 a = q[0], b = q[1];
        r.v[0] = a.x; r.v[1] = a.y; r.v[2] = a.z; r.v[3] = a.w;
        r.v[4] = b.x; r.v[5] = b.y; r.v[6] = b.z; r.v[7] = b.w;
    }
    return r;
}

__device__ __forceinline__ float block_reduce256(float v, float* sbuf) {
    int t = threadIdx.x;
    sbuf[t] = v;
    __syncthreads();
    for (int s = 128; s > 0; s >>= 1) {
        if (t < s) sbuf[t] += sbuf[t + s];
        __syncthreads();
    }
    float r = sbuf[0];
    __syncthreads();
    return r;
}

__device__ __forceinline__ float block_reduce_max256(float v, float* sbuf) {
    int t = threadIdx.x;
    sbuf[t] = v;
    __syncthreads();
    for (int s = 128; s > 0; s >>= 1) {
        if (t < s) sbuf[t] = fmaxf(sbuf[t], sbuf[t + s]);
        __syncthreads();
    }
    float r = sbuf[0];
    __syncthreads();
    return r;
}

// ---------------- kernel 1: probe dtype, zero sums region + accumulators ----
// grid 512 x 256: each thread zeroes one float4 of the means region
__global__ void k_zero(const void* video_scores, float* ws) {
    int gid = blockIdx.x * 256 + threadIdx.x;
    float4* m4 = (float4*)(ws + WS_MEANS);
    if (gid < MEANS_N / 4) m4[gid] = make_float4(0.f, 0.f, 0.f, 0.f);
    if (gid == 0) {
        const unsigned short* u = (const unsigned short*)video_scores;
        int cnt = 0;
        for (int i = 0; i < 64; i++) {
            unsigned short h = u[2 * i];
            int e = (h >> 7) & 0xFF;
            int sgn = (h >> 15) & 1;
            if (!sgn && e >= 90 && e <= 126) cnt++;
        }
        ((int*)ws)[0] = (cnt >= 56) ? 1 : 0;
        ws[8] = 0.f; ws[9] = 0.f; ws[10] = 0.f; ws[11] = 0.f;
    }
}

// ---------------- kernel 2: per-batch channel sums of HA/EA/HB/EB -----------
// grid 1280 = arr(4) * b(64) * chunk(5 of 30 rows); block 256 x 8 channels
__global__ void k_means(const void* HA, const void* EA, const void* HB, const void* EB,
                        float* ws) {
    int bf = ((const int*)ws)[0];
    int bi = blockIdx.x;
    int chunk = bi % 5;
    int b = (bi / 5) & 63;
    int arr = bi / 320;
    const void* src = (arr == 0) ? HA : (arr == 1) ? EA : (arr == 2) ? HB : EB;
    int c0 = threadIdx.x * 8;
    float acc[8];
#pragma unroll
    for (int k = 0; k < 8; k++) acc[k] = 0.f;
    int j0 = chunk * 30;
    for (int j = j0; j < j0 + 30; j++) {
        F8 v = ld8(src, (b * 150 + j) * 2048 + c0, bf);
#pragma unroll
        for (int k = 0; k < 8; k++) acc[k] += v.v[k];
    }
    float* dst = ws + WS_MEANS + (arr * 64 + b) * 2048 + c0;
#pragma unroll
    for (int k = 0; k < 8; k++) atomicAdd(dst + k, acc[k]);
}

// ---------------- kernel 3: raw dots q.neg_row + row sumsq ------------------
// grid 1920 = which(2) * b(64) * chunk(15 of 10 rows); block 256 = 4 waves
__global__ void k_dots(const void* EA, const void* EB, float* ws) {
    int bf = ((const int*)ws)[0];
    __shared__ float qs[2048];
    int bi = blockIdx.x;
    int which = bi / 960;
    int rem = bi % 960;
    int b = rem / 15;
    int chunk = rem % 15;
    const float* q = ws + WS_MEANS + ((which == 0 ? 0 : 2) * 64 + b) * 2048;
    for (int i = threadIdx.x; i < 2048; i += 256) qs[i] = q[i];
    __syncthreads();
    const void* neg = (which == 0) ? EB : EA;
    int lane = threadIdx.x & 63;
    int wid = threadIdx.x >> 6;
    for (int j = chunk * 10 + wid; j < chunk * 10 + 10; j += 4) {
        int base = (b * 150 + j) * 2048;
        float dot = 0.f, nsq = 0.f;
#pragma unroll
        for (int it = 0; it < 4; it++) {
            int off = it * 512 + lane * 8;
            F8 v = ld8(neg, base + off, bf);
#pragma unroll
            for (int k = 0; k < 8; k++) {
                float x = v.v[k];
                dot += x * qs[off + k];
                nsq += x * x;
            }
        }
        for (int s = 32; s > 0; s >>= 1) {
            dot += __shfl_down(dot, s);
            nsq += __shfl_down(nsq, s);
        }
        if (lane == 0) {
            ws[WS_DOTS + (which * 64 + b) * 150 + j] = dot;
            ws[WS_NSQ + (which * 64 + b) * 150 + j] = nsq;
        }
    }
}

// ---------------- kernel 4: fused cls + rel + act ---------------------------
// grid 66: block 0 = cls; blocks 1..32 = rel + act-part2; blocks 33..65 = act-part1
__global__ void k_small(const void* vs, const void* label,
                        const void* res, const void* red,
                        const void* a0, const void* a2, float* ws) {
    int bf = ((const int*)ws)[0];
    __shared__ float sbuf[256];
    __shared__ float rowsum[64];
    __shared__ float sa0[64 * 40];
    __shared__ float sa2[64 * 40];
    int t = threadIdx.x;
    int bi = blockIdx.x;

    if (bi == 0) {
        // ---- loss_cls ----
        if (t < 64) {
            float s = 0.f;
            for (int c = 0; c < 20; c++) s += ldf(label, t * 20 + c, bf);
            rowsum[t] = s;
        }
        __syncthreads();
        float local = 0.f;
        for (int i = t; i < 1280; i += 256) {
            int b = i / 20;
            float lab = ldf(label, i, bf) / rowsum[b];
            float v = ldf(vs, i, bf);
            v = fminf(fmaxf(v, EPSF), 1.f - EPSF);
            local += lab * logf(v) + (1.f - lab) * log1pf(-v);
        }
        float s = block_reduce256(local, sbuf);
        if (t == 0) ws[8] = -s / 1280.f;
    } else if (bi <= 32) {
        // ---- loss_rel + act part2 ----
        int base = (bi - 1) * 256 + t;
        int stride = 32 * 256;
        float lrel = 0.f;
        for (int i = base; i < 96000; i += stride) {
            float sv = ldf(res, i, bf);
            float dv = ldf(red, i, bf);
            lrel += (1.f - sv) * (1.f - sv) + dv * dv;
        }
        float s = block_reduce256(lrel, sbuf);
        if (t == 0) atomicAdd(&ws[9], s * (1.f / 96000.f));
        float lact = 0.f;
        for (int i = base; i < 48000; i += stride) {
            float x = ldf(a0, i, bf) - ldf(a2, i, bf);
            lact += x * x;
        }
        s = block_reduce256(lact, sbuf);
        if (t == 0) atomicAdd(&ws[10], s * (0.1f / 64.f));
    } else {
        // ---- act part1: 750x11 windows, sum over batch; LDS staging ----
        int abi = bi - 33;
        int B0 = abi * 256;
        int B1 = min(B0 + 255, 8249);
        int tmin = B0 / 11, tmax = B1 / 11;
        int lo = max(0, tmin - 6);
        int hi = min(749, tmax + 5);
        int ncol = hi - lo + 1;  // <= 36
        int total = 64 * ncol;
        for (int i = t; i < total; i += 256) {
            int b = i / ncol;
            int col = i % ncol;
            sa0[i] = ldf(a0, b * 750 + lo + col, bf);
            sa2[i] = ldf(a2, b * 750 + lo + col, bf);
        }
        __syncthreads();
        int id = B0 + t;
        float val = 0.f;
        if (id < 8250) {
            int tt = id / 11;
            int d = id % 11;
            int c = min(max(tt + d - 6, 0), 749);
            int ct = tt - lo, cc = c - lo;
            float wsum = 0.f, asum = 0.f;
            for (int b = 0; b < 64; b++) {
                float x = sa0[b * ncol + ct];
                float y = sa0[b * ncol + cc];
                wsum += (x - y) * (x - y);
                float p = sa2[b * ncol + ct];
                float q = sa2[b * ncol + cc];
                asum += fabsf(p - q);
            }
            val = __expf(-0.5f * wsum) * (asum * (1.f / 64.f));
        }
        float s = block_reduce256(val, sbuf);
        if (t == 0) atomicAdd(&ws[10], s);
    }
}

// ---------------- kernel 5: NCE norms + logsumexp per (which,b) -------------
// grid 128; block 256
__global__ void k_nce(const void* att, float* ws) {
    int bf = ((const int*)ws)[0];
    __shared__ float sbuf[256];
    int t = threadIdx.x;
    int w = blockIdx.x >> 6;
    int b = blockIdx.x & 63;
    const float* qv = ws + WS_MEANS + ((w == 0 ? 0 : 2) * 64 + b) * 2048;
    const float* kv = ws + WS_MEANS + ((w == 0 ? 1 : 3) * 64 + b) * 2048;
    float p0 = 0.f, p1 = 0.f, p2 = 0.f;
    for (int c = t; c < 2048; c += 256) {
        float qa = qv[c], ka = kv[c];
        p0 += qa * qa; p1 += ka * ka; p2 += qa * ka;
    }
    float nq = block_reduce256(p0, sbuf);
    float nk = block_reduce256(p1, sbuf);
    float dd = block_reduce256(p2, sbuf);
    float invq = rsqrtf(nq);
    float lpos = dd * invq * rsqrtf(nk) * (1.f / T_NCE);
    float lg = -INFINITY;
    if (t < 150) {
        float raw = ws[WS_DOTS + (w * 64 + b) * 150 + t];
        float nn = ws[WS_NSQ + (w * 64 + b) * 150 + t];
        float a = ldf(att, b * 300 + w * 150 + t, bf);
        lg = a * raw * invq * rsqrtf(nn) * (1.f / T_NCE);
    }
    float m = block_reduce_max256(lg, sbuf);
    m = fmaxf(m, lpos);
    float ex = (t < 150) ? expf(lg - m) : 0.f;
    float ssum = block_reduce256(ex, sbuf) + expf(lpos - m);
    if (t == 0) {
        float loss = (m + logf(ssum)) - lpos;  // -log_softmax[0]
        atomicAdd(&ws[11], loss * (1.f / 64.f));
    }
}

// ---------------- kernel 6: final combine -----------------------------------
__global__ void k_out(float* ws, void* out) {
    if (threadIdx.x == 0) {
        int bf = ((const int*)ws)[0];
        float cls = ws[8], rel = ws[9], act = ws[10], snico = ws[11];
        float total = cls + 0.01f * snico + act + 0.1f * rel;
        if (bf) {
            __hip_bfloat16* o = (__hip_bfloat16*)out;
            o[0] = __float2bfloat16(total);
            o[1] = __float2bfloat16(cls);
            o[2] = __float2bfloat16(snico);
            o[3] = __float2bfloat16(act);
            o[4] = __float2bfloat16(rel);
        } else {
            float* o = (float*)out;
            o[0] = total; o[1] = cls; o[2] = snico; o[3] = act; o[4] = rel;
        }
    }
}

extern "C" void kernel_launch(void* const* d_in, const int* in_sizes, int n_in,
                              void* d_out, int out_size, void* d_ws, size_t ws_size,
                              hipStream_t stream) {
    const void* video_scores = d_in[0];
    const void* label = d_in[1];
    const void* HA = d_in[2];
    const void* EA = d_in[3];
    const void* HB = d_in[4];
    const void* EB = d_in[5];
    const void* re_s = d_in[6];
    const void* re_d = d_in[7];
    const void* actioness = d_in[8];
    const void* actioness_2 = d_in[9];
    const void* att = d_in[10];
    float* ws = (float*)d_ws;

    k_zero<<<512, 256, 0, stream>>>(video_scores, ws);
    k_means<<<1280, 256, 0, stream>>>(HA, EA, HB, EB, ws);
    k_dots<<<1920, 256, 0, stream>>>(EA, EB, ws);
    k_small<<<66, 256, 0, stream>>>(video_scores, label, re_s, re_d,
                                    actioness, actioness_2, ws);
    k_nce<<<128, 256, 0, stream>>>(att, ws);
    k_out<<<1, 1, 0, stream>>>(ws, d_out);
}